// Round 4
// baseline (140.559 us; speedup 1.0000x reference)
//
#include <hip/hip_runtime.h>
#include <hip/hip_bf16.h>

// Problem constants
#define NB    8      // batch
#define NG    64     // c_inp groups (g)
#define NCI   16     // conv in channels (ci)
#define NC0   16     // conv out channels (c0)
#define NJ    64     // c_out (j)
#define IH    64
#define IW    64
#define OH    62
#define OW    62
#define IPIX  4096   // 64*64
#define OPIX  3844   // 62*62

typedef __attribute__((ext_vector_type(8))) short  short8;
typedef __attribute__((ext_vector_type(4))) short  short4v;
typedef __attribute__((ext_vector_type(4))) float  float4v;

__device__ __forceinline__ unsigned short f2bf(float f) {
    unsigned int u = __builtin_bit_cast(unsigned int, f);
    unsigned int r = (u + 0x7fffu + ((u >> 16) & 1u)) >> 16;
    return (unsigned short)r;
}

// ---------------------------------------------------------------------------
// prep: blocks 0..7 build Wm B-fragments (bf16) for mix (jt = bi>>1, kh = bi&1)
//       block 8 builds conv K-fragments Kb (K padded to 160 contraction, bf16)
// Fragment convention (16x16x32 bf16): free index = lane&15, k = (lane>>4)*8+i.
// ---------------------------------------------------------------------------
__global__ __launch_bounds__(64) void prep_kernel(const float* __restrict__ K,
                                                  const float* __restrict__ c0_,
                                                  const float* __restrict__ c1_,
                                                  const float* __restrict__ c2_,
                                                  unsigned short* __restrict__ wmb,
                                                  unsigned short* __restrict__ kb) {
    int bi = blockIdx.x;
    int l  = threadIdx.x;
    if (bi < 8) {
        int jt = bi >> 1, kh = bi & 1;
        int j = jt * 16 + (l & 15);
        int j1 = j >> 4, j2 = (j >> 2) & 3, j3 = j & 3;
        for (int i = 0; i < 8; ++i) {
            int g = kh * 32 + (l >> 4) * 8 + i;
            int i1 = g >> 4, i2 = (g >> 2) & 3, i3 = g & 3;
            float s = 0.f;
            #pragma unroll
            for (int r1 = 0; r1 < 8; ++r1) {
                float a = c0_[(i1 * 4 + j1) * 8 + r1];
                float t = 0.f;
                #pragma unroll
                for (int r2 = 0; r2 < 8; ++r2) {
                    t += c1_[((r1 * 4 + i2) * 4 + j2) * 8 + r2] *
                         c2_[(r2 * 4 + i3) * 4 + j3];
                }
                s += a * t;
            }
            wmb[(bi * 64 + l) * 8 + i] = f2bf(s);
        }
    } else {
        int c0i = l & 15, q = l >> 4;
        for (int f = 0; f < 5; ++f) {
            int tap = f * 2 + (q >> 1);  // 0..9; 9 = zero pad
            for (int i = 0; i < 8; ++i) {
                int ci = (q & 1) * 8 + i;
                float v = (tap < 9) ? K[(c0i * 16 + ci) * 9 + tap] : 0.f;
                kb[(f * 64 + l) * 8 + i] = f2bf(v);
            }
        }
    }
}

// ---------------------------------------------------------------------------
// xbf: pure sequential fp32 -> bf16 copy-convert of x, SAME [c][px] layout.
// Rationale (R1-R3 post-mortem): reads of x at 16KB channel stride are capped
// ~1.7 TB/s at DRAM regardless of occupancy/segmentation; sequential streams
// hit ~6-7 TB/s. So stream x through once sequentially, and let the strided
// gather in mix2b hit the 67 MB MALL-resident bf16 copy instead of DRAM.
// grid = 2048 x 256, 8 floats/thread/sweep, 8 sweeps.
// ---------------------------------------------------------------------------
__global__ __launch_bounds__(256) void xbf_kernel(const float* __restrict__ x,
                                                  unsigned short* __restrict__ xb) {
    const size_t total  = (size_t)NB * 1024 * IPIX;               // 33.5M floats
    const size_t stride = (size_t)gridDim.x * 256 * 8;
    size_t i = ((size_t)blockIdx.x * 256 + threadIdx.x) * 8;
    for (; i < total; i += stride) {
        float4v a = *(const float4v*)(x + i);
        float4v b = *(const float4v*)(x + i + 4);
        short8 o;
        o[0] = (short)f2bf(a[0]); o[1] = (short)f2bf(a[1]);
        o[2] = (short)f2bf(a[2]); o[3] = (short)f2bf(a[3]);
        o[4] = (short)f2bf(b[0]); o[5] = (short)f2bf(b[1]);
        o[6] = (short)f2bf(b[2]); o[7] = (short)f2bf(b[3]);
        *(short8*)(xb + i) = o;
    }
}

// ---------------------------------------------------------------------------
// mix2b: Z[b][p][j][ci] (bf16) = sum_g xb[g,ci,p] * Wm[g,j]  via MFMA.
// Identical structure/LDS layout/swizzle/compute to the proven R1 mix2; the
// staging gather now reads the MALL-resident bf16 copy (short4 loads, no
// conversion). Values bit-identical (f2bf applied in xbf instead).
// grid = 8 * 128 = 1024 blocks of 256, 32 px/block.
// ---------------------------------------------------------------------------
__global__ __launch_bounds__(256) void mix2b_kernel(const unsigned short* __restrict__ xb,
                                                    const unsigned short* __restrict__ wmb,
                                                    unsigned short* __restrict__ Z) {
    __shared__ __align__(16) char smem[32 * 2048];  // 64 KB
    int t  = threadIdx.x;
    int b  = blockIdx.x >> 7;
    int p0 = (blockIdx.x & 127) * 32;

    // ---- stage xb -> LDS [px][ci][g] bf16, swizzled ----
    int pq  = (t & 7) * 4;   // pixel base: 0,4,...,28
    int grp = t >> 3;        // 0..31 channel-quad group
    const unsigned short* xbp = xb + (size_t)b * 1024 * IPIX + p0 + pq;
    #pragma unroll 2
    for (int it = 0; it < 8; ++it) {
        int qd = it * 32 + grp;       // 0..255 channel-quads
        int gq = qd & 15, ci = qd >> 4;
        int g0 = gq * 4;
        const unsigned short* xp = xbp + (size_t)(g0 * 16 + ci) * IPIX;
        short4v v0 = *(const short4v*)(xp);                 // g0+0, px pq..pq+3
        short4v v1 = *(const short4v*)(xp + 16 * IPIX);     // g0+1
        short4v v2 = *(const short4v*)(xp + 32 * IPIX);     // g0+2
        short4v v3 = *(const short4v*)(xp + 48 * IPIX);     // g0+3
        #pragma unroll
        for (int pp = 0; pp < 4; ++pp) {
            int px = pq + pp;
            short4v u;
            u[0] = v0[pp]; u[1] = v1[pp]; u[2] = v2[pp]; u[3] = v3[pp];
            int chunk = (g0 >> 3) ^ (ci & 7) ^ (px & 7);
            *(short4v*)(smem + px * 2048 + ci * 128 + chunk * 16 + (g0 & 7) * 2) = u;
        }
    }
    __syncthreads();

    // ---- compute ----
    int lane = t & 63, wv = t >> 6;
    int ln = lane & 15, quad = lane >> 4;

    short8 bf[8];
    #pragma unroll
    for (int q8 = 0; q8 < 8; ++q8)
        bf[q8] = *(const short8*)(wmb + (q8 * 64 + lane) * 8);  // [jt*2+kh]

    unsigned short* Zb = Z + (size_t)(b * IPIX + p0) * 1024;
    for (int k = 0; k < 8; ++k) {
        int pl = wv * 8 + k;
        const char* arow = smem + pl * 2048 + ln * 128;
        int sw = (ln & 7) ^ (pl & 7);
        short8 a0 = *(const short8*)(arow + (((0 + quad) ^ sw) * 16));
        short8 a1 = *(const short8*)(arow + (((4 + quad) ^ sw) * 16));
        unsigned short* zp = Zb + (size_t)pl * 1024 + ln * 16 + quad * 4;
        #pragma unroll
        for (int jt = 0; jt < 4; ++jt) {
            float4v acc = {0.f, 0.f, 0.f, 0.f};
            acc = __builtin_amdgcn_mfma_f32_16x16x32_bf16(a0, bf[jt * 2 + 0], acc, 0, 0, 0);
            acc = __builtin_amdgcn_mfma_f32_16x16x32_bf16(a1, bf[jt * 2 + 1], acc, 0, 0, 0);
            short4v o;
            o[0] = (short)f2bf(acc[0]); o[1] = (short)f2bf(acc[1]);
            o[2] = (short)f2bf(acc[2]); o[3] = (short)f2bf(acc[3]);
            *(short4v*)(zp + jt * 256) = o;
        }
    }
}

// ---------------------------------------------------------------------------
// conv2: out[b,c0,p,j] = bias[j] + sum_{ci,tap} K[c0,ci,tap] * Z[b, p+tap, j, ci]
// MFMA with A = Z (m = j), B = K (n = c0), K-dim = 160 (9 taps x 16 ci, padded).
// D rows are 4 CONSECUTIVE j per lane -> single float4 output store per lane
// per pixel. grid = 8 * 62 * 2 = 992 blocks of 256; wave = j-tile, 31 pixels.
// ---------------------------------------------------------------------------
__global__ __launch_bounds__(256, 4) void conv2_kernel(const unsigned short* __restrict__ Z,
                                                       const unsigned short* __restrict__ kb,
                                                       const float* __restrict__ bias,
                                                       float* __restrict__ out) {
    int t = threadIdx.x, lane = t & 63, wv = t >> 6;
    int ln = lane & 15, quad = lane >> 4;
    int blk = blockIdx.x;
    int xh = blk & 1;
    int y  = (blk >> 1) % OH;
    int b  = blk / (OH * 2);

    short8 af[5];
    int off[5];
    #pragma unroll
    for (int f = 0; f < 5; ++f) {
        af[f] = *(const short8*)(kb + (f * 64 + lane) * 8);
        int tap = f * 2 + (quad >> 1);
        if (tap > 8) tap = 8;              // pad chunk: K is zero, any valid addr
        int dy = tap / 3, dx = tap % 3;
        off[f] = (dy * IW + dx) * 1024 + (wv * 16 + ln) * 16 + (quad & 1) * 8;
    }
    // bias along j (acc rows): j = wv*16 + quad*4 + r
    float4v bv = *(const float4v*)(bias + wv * 16 + quad * 4);

    const unsigned short* zbase = Z + (size_t)(b * IPIX + y * IW + xh * 31) * 1024;
    // per-lane c0 = ln (acc cols); j base = wv*16 + quad*4
    float* ob = out + ((size_t)(b * NC0 + ln) * OPIX + (size_t)(y * OW + xh * 31)) * NJ
                    + wv * 16 + quad * 4;

    #pragma unroll 2
    for (int xi = 0; xi < 31; ++xi) {
        const unsigned short* zp = zbase + (size_t)xi * 1024;
        short8 z0 = *(const short8*)(zp + off[0]);
        short8 z1 = *(const short8*)(zp + off[1]);
        short8 z2 = *(const short8*)(zp + off[2]);
        short8 z3 = *(const short8*)(zp + off[3]);
        short8 z4 = *(const short8*)(zp + off[4]);
        float4v acc = bv;
        acc = __builtin_amdgcn_mfma_f32_16x16x32_bf16(z0, af[0], acc, 0, 0, 0);
        acc = __builtin_amdgcn_mfma_f32_16x16x32_bf16(z1, af[1], acc, 0, 0, 0);
        acc = __builtin_amdgcn_mfma_f32_16x16x32_bf16(z2, af[2], acc, 0, 0, 0);
        acc = __builtin_amdgcn_mfma_f32_16x16x32_bf16(z3, af[3], acc, 0, 0, 0);
        acc = __builtin_amdgcn_mfma_f32_16x16x32_bf16(z4, af[4], acc, 0, 0, 0);
        *(float4v*)(ob + (size_t)xi * NJ) = acc;
    }
}

// ---------------------------------------------------------------------------
// Fallback path (small ws): round-1 kernels, fp32 throughout.
// ---------------------------------------------------------------------------
__global__ __launch_bounds__(64) void wm_kernel(const float* __restrict__ core0,
                                                const float* __restrict__ core1,
                                                const float* __restrict__ core2,
                                                float* __restrict__ Wm) {
    int g = threadIdx.x;
    int i1 = g >> 4, i2 = (g >> 2) & 3, i3 = g & 3;
    for (int j = 0; j < NJ; ++j) {
        int j1 = j >> 4, j2 = (j >> 2) & 3, j3 = j & 3;
        float s = 0.f;
        #pragma unroll
        for (int r1 = 0; r1 < 8; ++r1) {
            float a = core0[(i1 * 4 + j1) * 8 + r1];
            float t = 0.f;
            #pragma unroll
            for (int r2 = 0; r2 < 8; ++r2) {
                t += core1[((r1 * 4 + i2) * 4 + j2) * 8 + r2] *
                     core2[(r2 * 4 + i3) * 4 + j3];
            }
            s += a * t;
        }
        Wm[g * NJ + j] = s;
    }
}

__global__ __launch_bounds__(256) void fused_fallback(const float* __restrict__ x,
                                                      const float* __restrict__ K,
                                                      const float* __restrict__ Wm,
                                                      const float* __restrict__ bias,
                                                      float* __restrict__ out) {
    __shared__ float wlds[NG * NJ];
    __shared__ float klds[NCI * 9];
    int blk  = blockIdx.x;
    int pblk = blk & 15;
    int c0   = (blk >> 4) & 15;
    int b    = blk >> 8;
    for (int i = threadIdx.x; i < NG * NJ; i += 256) wlds[i] = Wm[i];
    for (int i = threadIdx.x; i < NCI * 9; i += 256) klds[i] = K[c0 * NCI * 9 + i];
    __syncthreads();

    int pix = pblk * 256 + threadIdx.x;
    if (pix >= OPIX) return;
    int y  = pix / OW;
    int xx = pix % OW;

    float acc[NJ];
    #pragma unroll
    for (int j = 0; j < NJ; ++j) acc[j] = 0.f;

    for (int g = 0; g < NG; ++g) {
        float c = 0.f;
        const float* xb = x + ((size_t)(b * NG + g) * NCI) * IPIX;
        for (int ci = 0; ci < NCI; ++ci) {
            #pragma unroll
            for (int dy = 0; dy < 3; ++dy) {
                #pragma unroll
                for (int dx = 0; dx < 3; ++dx) {
                    c += xb[ci * IPIX + (y + dy) * IW + (xx + dx)] *
                         klds[ci * 9 + dy * 3 + dx];
                }
            }
        }
        const float4* wp = (const float4*)&wlds[g * NJ];
        #pragma unroll
        for (int j4 = 0; j4 < 16; ++j4) {
            float4 w = wp[j4];
            acc[j4 * 4 + 0] += w.x * c;
            acc[j4 * 4 + 1] += w.y * c;
            acc[j4 * 4 + 2] += w.z * c;
            acc[j4 * 4 + 3] += w.w * c;
        }
    }
    #pragma unroll
    for (int j = 0; j < NJ; ++j) {
        out[(((size_t)(b * NC0 + c0) * OPIX) + pix) * NJ + j] = acc[j] + bias[j];
    }
}

extern "C" void kernel_launch(void* const* d_in, const int* in_sizes, int n_in,
                              void* d_out, int out_size, void* d_ws, size_t ws_size,
                              hipStream_t stream) {
    const float* x     = (const float*)d_in[0];
    const float* K     = (const float*)d_in[1];
    const float* core0 = (const float*)d_in[2];
    const float* core1 = (const float*)d_in[3];
    const float* core2 = (const float*)d_in[4];
    const float* bias  = (const float*)d_in[5];
    float* out = (float*)d_out;

    const size_t z_off   = 16384;
    const size_t z_bytes = (size_t)NB * IPIX * NJ * NCI * sizeof(unsigned short);  // 67.1 MB

    if (ws_size >= z_off + 2 * z_bytes + 256) {
        unsigned short* wmb = (unsigned short*)d_ws;                    // 8 KB
        unsigned short* kb  = (unsigned short*)((char*)d_ws + 8192);    // 5 KB
        unsigned short* xb  = (unsigned short*)((char*)d_ws + z_off);
        unsigned short* Z   = (unsigned short*)((char*)d_ws + z_off + z_bytes);
        prep_kernel<<<9, 64, 0, stream>>>(K, core0, core1, core2, wmb, kb);
        xbf_kernel<<<2048, 256, 0, stream>>>(x, xb);
        mix2b_kernel<<<NB * 128, 256, 0, stream>>>(xb, wmb, Z);
        conv2_kernel<<<NB * OH * 2, 256, 0, stream>>>(Z, kb, bias, out);
    } else {
        float* Wm = (float*)d_ws;
        wm_kernel<<<1, 64, 0, stream>>>(core0, core1, core2, Wm);
        fused_fallback<<<NB * NC0 * 16, 256, 0, stream>>>(x, K, Wm, bias, out);
    }
}

// Round 5
// 110.469 us; speedup vs baseline: 1.2724x; 1.2724x over previous
//
#include <hip/hip_runtime.h>
#include <hip/hip_bf16.h>

// Problem constants
#define NB    8      // batch
#define NG    64     // c_inp groups (g)
#define NCI   16     // conv in channels (ci)
#define NC0   16     // conv out channels (c0)
#define NJ    64     // c_out (j)
#define IH    64
#define IW    64
#define OH    62
#define OW    62
#define IPIX  4096   // 64*64
#define OPIX  3844   // 62*62

typedef __attribute__((ext_vector_type(8))) short  short8;
typedef __attribute__((ext_vector_type(4))) short  short4v;
typedef __attribute__((ext_vector_type(4))) float  float4v;

__device__ __forceinline__ unsigned short f2bf(float f) {
    unsigned int u = __builtin_bit_cast(unsigned int, f);
    unsigned int r = (u + 0x7fffu + ((u >> 16) & 1u)) >> 16;
    return (unsigned short)r;
}

// ---------------------------------------------------------------------------
// prep: blocks 0..7 build Wm B-fragments (bf16) for mix (jt = bi>>1, kh = bi&1)
//       block 8 builds conv K-fragments Kb (K padded to 160 contraction, bf16)
// Fragment convention (16x16x32 bf16): free index = lane&15, k = (lane>>4)*8+i.
// ---------------------------------------------------------------------------
__global__ __launch_bounds__(64) void prep_kernel(const float* __restrict__ K,
                                                  const float* __restrict__ c0_,
                                                  const float* __restrict__ c1_,
                                                  const float* __restrict__ c2_,
                                                  unsigned short* __restrict__ wmb,
                                                  unsigned short* __restrict__ kb) {
    int bi = blockIdx.x;
    int l  = threadIdx.x;
    if (bi < 8) {
        int jt = bi >> 1, kh = bi & 1;
        int j = jt * 16 + (l & 15);
        int j1 = j >> 4, j2 = (j >> 2) & 3, j3 = j & 3;
        for (int i = 0; i < 8; ++i) {
            int g = kh * 32 + (l >> 4) * 8 + i;
            int i1 = g >> 4, i2 = (g >> 2) & 3, i3 = g & 3;
            float s = 0.f;
            #pragma unroll
            for (int r1 = 0; r1 < 8; ++r1) {
                float a = c0_[(i1 * 4 + j1) * 8 + r1];
                float t = 0.f;
                #pragma unroll
                for (int r2 = 0; r2 < 8; ++r2) {
                    t += c1_[((r1 * 4 + i2) * 4 + j2) * 8 + r2] *
                         c2_[(r2 * 4 + i3) * 4 + j3];
                }
                s += a * t;
            }
            wmb[(bi * 64 + l) * 8 + i] = f2bf(s);
        }
    } else {
        int c0i = l & 15, q = l >> 4;
        for (int f = 0; f < 5; ++f) {
            int tap = f * 2 + (q >> 1);  // 0..9; 9 = zero pad
            for (int i = 0; i < 8; ++i) {
                int ci = (q & 1) * 8 + i;
                float v = (tap < 9) ? K[(c0i * 16 + ci) * 9 + tap] : 0.f;
                kb[(f * 64 + l) * 8 + i] = f2bf(v);
            }
        }
    }
}

// ---------------------------------------------------------------------------
// mixs: fused transpose+mix. Z[b][p][j][ci] (bf16) = sum_g x[b,g,ci,p]*Wm[g,j].
// R5 change vs mix2: LDS tile rotated to 64 px x 1024 ch (128 KB, legal on
// gfx950). Staging reads are 16-lane x 16 B = 256-B CONTIGUOUS segments (one
// full tile-row per load) -- 2x R1's 128-B segments, testing the per-CU
// request-slot model (scattered reads capped at ~48-64 slots x ~900ns; more
// bytes per slot => proportional BW). Staging pack (4 consecutive g -> b64),
// LDS layout/swizzle, compute, and Z-write are the proven mix2 code verbatim
// (px range 32 -> 64; 8 waves x 8 px). Bit-identical numerics.
// grid = 8b * 64 pxblk = 512 blocks of 512; 1 block/CU (128 KB LDS).
// ---------------------------------------------------------------------------
__global__ __launch_bounds__(512, 2) void mixs_kernel(const float* __restrict__ x,
                                                      const unsigned short* __restrict__ wmb,
                                                      unsigned short* __restrict__ Z) {
    __shared__ __align__(16) char smem[64 * 2048];  // 128 KB
    int t  = threadIdx.x;
    int b  = blockIdx.x >> 6;
    int p0 = (blockIdx.x & 63) * 64;

    // ---- stage x -> LDS [px][ci][g] bf16, swizzled ----
    // 16 lanes (t&15) cover the 64-px row of one channel: 256-B segment/load.
    int px4 = (t & 15) * 4;   // px quad base: 0,4,...,60
    int qr  = t >> 4;         // 0..31 quad-row group
    const float* xb = x + (size_t)b * 1024 * IPIX + p0 + px4;
    #pragma unroll 2
    for (int it = 0; it < 8; ++it) {
        int qd = it * 32 + qr;        // 0..255 channel-quads (ci 16 x gq 16)
        int gq = qd & 15, ci = qd >> 4;
        int g0 = gq * 4;
        const float* xp = xb + (size_t)(g0 * 16 + ci) * IPIX;
        float4v v0 = *(const float4v*)(xp);                 // g0+0, px px4..px4+3
        float4v v1 = *(const float4v*)(xp + 16 * IPIX);     // g0+1
        float4v v2 = *(const float4v*)(xp + 32 * IPIX);     // g0+2
        float4v v3 = *(const float4v*)(xp + 48 * IPIX);     // g0+3
        #pragma unroll
        for (int pp = 0; pp < 4; ++pp) {
            int px = px4 + pp;
            short4v u;
            u[0] = (short)f2bf(v0[pp]);
            u[1] = (short)f2bf(v1[pp]);
            u[2] = (short)f2bf(v2[pp]);
            u[3] = (short)f2bf(v3[pp]);
            int chunk = (g0 >> 3) ^ (ci & 7) ^ (px & 7);
            *(short4v*)(smem + px * 2048 + ci * 128 + chunk * 16 + (g0 & 7) * 2) = u;
        }
    }
    __syncthreads();

    // ---- compute (mix2 verbatim, 8 waves x 8 px) ----
    int lane = t & 63, wv = t >> 6;     // wv 0..7
    int ln = lane & 15, quad = lane >> 4;

    short8 bf[8];
    #pragma unroll
    for (int q8 = 0; q8 < 8; ++q8)
        bf[q8] = *(const short8*)(wmb + (q8 * 64 + lane) * 8);  // [jt*2+kh]

    unsigned short* Zb = Z + (size_t)(b * IPIX + p0) * 1024;
    for (int k = 0; k < 8; ++k) {
        int pl = wv * 8 + k;            // 0..63
        const char* arow = smem + pl * 2048 + ln * 128;
        int sw = (ln & 7) ^ (pl & 7);
        short8 a0 = *(const short8*)(arow + (((0 + quad) ^ sw) * 16));
        short8 a1 = *(const short8*)(arow + (((4 + quad) ^ sw) * 16));
        unsigned short* zp = Zb + (size_t)pl * 1024 + ln * 16 + quad * 4;
        #pragma unroll
        for (int jt = 0; jt < 4; ++jt) {
            float4v acc = {0.f, 0.f, 0.f, 0.f};
            acc = __builtin_amdgcn_mfma_f32_16x16x32_bf16(a0, bf[jt * 2 + 0], acc, 0, 0, 0);
            acc = __builtin_amdgcn_mfma_f32_16x16x32_bf16(a1, bf[jt * 2 + 1], acc, 0, 0, 0);
            short4v o;
            o[0] = (short)f2bf(acc[0]); o[1] = (short)f2bf(acc[1]);
            o[2] = (short)f2bf(acc[2]); o[3] = (short)f2bf(acc[3]);
            *(short4v*)(zp + jt * 256) = o;
        }
    }
}

// ---------------------------------------------------------------------------
// conv2: out[b,c0,p,j] = bias[j] + sum_{ci,tap} K[c0,ci,tap] * Z[b, p+tap, j, ci]
// MFMA with A = Z (m = j), B = K (n = c0), K-dim = 160 (9 taps x 16 ci, padded).
// D rows are 4 CONSECUTIVE j per lane -> single float4 output store per lane
// per pixel. grid = 8 * 62 * 2 = 992 blocks of 256; wave = j-tile, 31 pixels.
// ---------------------------------------------------------------------------
__global__ __launch_bounds__(256, 4) void conv2_kernel(const unsigned short* __restrict__ Z,
                                                       const unsigned short* __restrict__ kb,
                                                       const float* __restrict__ bias,
                                                       float* __restrict__ out) {
    int t = threadIdx.x, lane = t & 63, wv = t >> 6;
    int ln = lane & 15, quad = lane >> 4;
    int blk = blockIdx.x;
    int xh = blk & 1;
    int y  = (blk >> 1) % OH;
    int b  = blk / (OH * 2);

    short8 af[5];
    int off[5];
    #pragma unroll
    for (int f = 0; f < 5; ++f) {
        af[f] = *(const short8*)(kb + (f * 64 + lane) * 8);
        int tap = f * 2 + (quad >> 1);
        if (tap > 8) tap = 8;              // pad chunk: K is zero, any valid addr
        int dy = tap / 3, dx = tap % 3;
        off[f] = (dy * IW + dx) * 1024 + (wv * 16 + ln) * 16 + (quad & 1) * 8;
    }
    // bias along j (acc rows): j = wv*16 + quad*4 + r
    float4v bv = *(const float4v*)(bias + wv * 16 + quad * 4);

    const unsigned short* zbase = Z + (size_t)(b * IPIX + y * IW + xh * 31) * 1024;
    // per-lane c0 = ln (acc cols); j base = wv*16 + quad*4
    float* ob = out + ((size_t)(b * NC0 + ln) * OPIX + (size_t)(y * OW + xh * 31)) * NJ
                    + wv * 16 + quad * 4;

    #pragma unroll 2
    for (int xi = 0; xi < 31; ++xi) {
        const unsigned short* zp = zbase + (size_t)xi * 1024;
        short8 z0 = *(const short8*)(zp + off[0]);
        short8 z1 = *(const short8*)(zp + off[1]);
        short8 z2 = *(const short8*)(zp + off[2]);
        short8 z3 = *(const short8*)(zp + off[3]);
        short8 z4 = *(const short8*)(zp + off[4]);
        float4v acc = bv;
        acc = __builtin_amdgcn_mfma_f32_16x16x32_bf16(z0, af[0], acc, 0, 0, 0);
        acc = __builtin_amdgcn_mfma_f32_16x16x32_bf16(z1, af[1], acc, 0, 0, 0);
        acc = __builtin_amdgcn_mfma_f32_16x16x32_bf16(z2, af[2], acc, 0, 0, 0);
        acc = __builtin_amdgcn_mfma_f32_16x16x32_bf16(z3, af[3], acc, 0, 0, 0);
        acc = __builtin_amdgcn_mfma_f32_16x16x32_bf16(z4, af[4], acc, 0, 0, 0);
        *(float4v*)(ob + (size_t)xi * NJ) = acc;
    }
}

// ---------------------------------------------------------------------------
// Fallback path (small ws): round-1 kernels, fp32 throughout.
// ---------------------------------------------------------------------------
__global__ __launch_bounds__(64) void wm_kernel(const float* __restrict__ core0,
                                                const float* __restrict__ core1,
                                                const float* __restrict__ core2,
                                                float* __restrict__ Wm) {
    int g = threadIdx.x;
    int i1 = g >> 4, i2 = (g >> 2) & 3, i3 = g & 3;
    for (int j = 0; j < NJ; ++j) {
        int j1 = j >> 4, j2 = (j >> 2) & 3, j3 = j & 3;
        float s = 0.f;
        #pragma unroll
        for (int r1 = 0; r1 < 8; ++r1) {
            float a = core0[(i1 * 4 + j1) * 8 + r1];
            float t = 0.f;
            #pragma unroll
            for (int r2 = 0; r2 < 8; ++r2) {
                t += core1[((r1 * 4 + i2) * 4 + j2) * 8 + r2] *
                     core2[(r2 * 4 + i3) * 4 + j3];
            }
            s += a * t;
        }
        Wm[g * NJ + j] = s;
    }
}

__global__ __launch_bounds__(256) void fused_fallback(const float* __restrict__ x,
                                                      const float* __restrict__ K,
                                                      const float* __restrict__ Wm,
                                                      const float* __restrict__ bias,
                                                      float* __restrict__ out) {
    __shared__ float wlds[NG * NJ];
    __shared__ float klds[NCI * 9];
    int blk  = blockIdx.x;
    int pblk = blk & 15;
    int c0   = (blk >> 4) & 15;
    int b    = blk >> 8;
    for (int i = threadIdx.x; i < NG * NJ; i += 256) wlds[i] = Wm[i];
    for (int i = threadIdx.x; i < NCI * 9; i += 256) klds[i] = K[c0 * NCI * 9 + i];
    __syncthreads();

    int pix = pblk * 256 + threadIdx.x;
    if (pix >= OPIX) return;
    int y  = pix / OW;
    int xx = pix % OW;

    float acc[NJ];
    #pragma unroll
    for (int j = 0; j < NJ; ++j) acc[j] = 0.f;

    for (int g = 0; g < NG; ++g) {
        float c = 0.f;
        const float* xb = x + ((size_t)(b * NG + g) * NCI) * IPIX;
        for (int ci = 0; ci < NCI; ++ci) {
            #pragma unroll
            for (int dy = 0; dy < 3; ++dy) {
                #pragma unroll
                for (int dx = 0; dx < 3; ++dx) {
                    c += xb[ci * IPIX + (y + dy) * IW + (xx + dx)] *
                         klds[ci * 9 + dy * 3 + dx];
                }
            }
        }
        const float4* wp = (const float4*)&wlds[g * NJ];
        #pragma unroll
        for (int j4 = 0; j4 < 16; ++j4) {
            float4 w = wp[j4];
            acc[j4 * 4 + 0] += w.x * c;
            acc[j4 * 4 + 1] += w.y * c;
            acc[j4 * 4 + 2] += w.z * c;
            acc[j4 * 4 + 3] += w.w * c;
        }
    }
    #pragma unroll
    for (int j = 0; j < NJ; ++j) {
        out[(((size_t)(b * NC0 + c0) * OPIX) + pix) * NJ + j] = acc[j] + bias[j];
    }
}

extern "C" void kernel_launch(void* const* d_in, const int* in_sizes, int n_in,
                              void* d_out, int out_size, void* d_ws, size_t ws_size,
                              hipStream_t stream) {
    const float* x     = (const float*)d_in[0];
    const float* K     = (const float*)d_in[1];
    const float* core0 = (const float*)d_in[2];
    const float* core1 = (const float*)d_in[3];
    const float* core2 = (const float*)d_in[4];
    const float* bias  = (const float*)d_in[5];
    float* out = (float*)d_out;

    const size_t z_off   = 16384;
    const size_t z_bytes = (size_t)NB * IPIX * NJ * NCI * sizeof(unsigned short);  // 67.1 MB

    if (ws_size >= z_off + z_bytes + 256) {
        unsigned short* wmb = (unsigned short*)d_ws;                    // 8 KB
        unsigned short* kb  = (unsigned short*)((char*)d_ws + 8192);    // 5 KB
        unsigned short* Z   = (unsigned short*)((char*)d_ws + z_off);
        prep_kernel<<<9, 64, 0, stream>>>(K, core0, core1, core2, wmb, kb);
        mixs_kernel<<<512, 512, 0, stream>>>(x, wmb, Z);
        conv2_kernel<<<NB * OH * 2, 256, 0, stream>>>(Z, kb, bias, out);
    } else {
        float* Wm = (float*)d_ws;
        wm_kernel<<<1, 64, 0, stream>>>(core0, core1, core2, Wm);
        fused_fallback<<<NB * NC0 * 16, 256, 0, stream>>>(x, K, Wm, bias, out);
    }
}

// Round 6
// 99.550 us; speedup vs baseline: 1.4119x; 1.1097x over previous
//
#include <hip/hip_runtime.h>
#include <hip/hip_bf16.h>

// Problem constants
#define NB    8      // batch
#define NG    64     // c_inp groups (g)
#define NCI   16     // conv in channels (ci)
#define NC0   16     // conv out channels (c0)
#define NJ    64     // c_out (j)
#define IH    64
#define IW    64
#define OH    62
#define OW    62
#define IPIX  4096   // 64*64
#define OPIX  3844   // 62*62

typedef __attribute__((ext_vector_type(8))) short  short8;
typedef __attribute__((ext_vector_type(4))) short  short4v;
typedef __attribute__((ext_vector_type(4))) float  float4v;

__device__ __forceinline__ unsigned short f2bf(float f) {
    unsigned int u = __builtin_bit_cast(unsigned int, f);
    unsigned int r = (u + 0x7fffu + ((u >> 16) & 1u)) >> 16;
    return (unsigned short)r;
}

// ---------------------------------------------------------------------------
// prep: blocks 0..7 build Wm fragments (bf16) (jt = bi>>1, kh = bi&1)
//       block 8 builds conv K-fragments kb (K padded to 160 contraction, bf16)
// Fragment convention (16x16x32 bf16): free index = lane&15, k = (lane>>4)*8+i.
// ---------------------------------------------------------------------------
__global__ __launch_bounds__(64) void prep_kernel(const float* __restrict__ K,
                                                  const float* __restrict__ c0_,
                                                  const float* __restrict__ c1_,
                                                  const float* __restrict__ c2_,
                                                  unsigned short* __restrict__ wmb,
                                                  unsigned short* __restrict__ kb) {
    int bi = blockIdx.x;
    int l  = threadIdx.x;
    if (bi < 8) {
        int jt = bi >> 1, kh = bi & 1;
        int j = jt * 16 + (l & 15);
        int j1 = j >> 4, j2 = (j >> 2) & 3, j3 = j & 3;
        for (int i = 0; i < 8; ++i) {
            int g = kh * 32 + (l >> 4) * 8 + i;
            int i1 = g >> 4, i2 = (g >> 2) & 3, i3 = g & 3;
            float s = 0.f;
            #pragma unroll
            for (int r1 = 0; r1 < 8; ++r1) {
                float a = c0_[(i1 * 4 + j1) * 8 + r1];
                float t = 0.f;
                #pragma unroll
                for (int r2 = 0; r2 < 8; ++r2) {
                    t += c1_[((r1 * 4 + i2) * 4 + j2) * 8 + r2] *
                         c2_[(r2 * 4 + i3) * 4 + j3];
                }
                s += a * t;
            }
            wmb[(bi * 64 + l) * 8 + i] = f2bf(s);
        }
    } else {
        int c0i = l & 15, q = l >> 4;
        for (int f = 0; f < 5; ++f) {
            int tap = f * 2 + (q >> 1);  // 0..9; 9 = zero pad
            for (int i = 0; i < 8; ++i) {
                int ci = (q & 1) * 8 + i;
                float v = (tap < 9) ? K[(c0i * 16 + ci) * 9 + tap] : 0.f;
                kb[(f * 64 + l) * 8 + i] = f2bf(v);
            }
        }
    }
}

// ---------------------------------------------------------------------------
// conv1: FIRST stage (ops commuted: conv before mix, exact by linearity).
// y[b][g*16+c0][yo*64+xo] (bf16, 64-padded rows) =
//     sum_{ci,tap} K[c0,ci,tap] * x[b, g*16+ci, yo+dy, xo+dx]
// Reads x SEQUENTIALLY (per (g,ci): 18-row = 4.5-KB contiguous windows) -> no
// strided-gather wall. MFMA: A = x-patch [m=px16][k=ci,tap], B = kb [k][n=c0]
// (kb reused as-is; zero-padded tap chunk makes clamped A-garbage harmless).
// Block = (b, g, band of 16 out-rows); LDS x-tile [r18][ci16][px68] bf16.
// grid = 8*64*4 = 2048 blocks of 256.
// ---------------------------------------------------------------------------
__global__ __launch_bounds__(256) void conv1_kernel(const float* __restrict__ x,
                                                    const unsigned short* __restrict__ kb,
                                                    unsigned short* __restrict__ y) {
    __shared__ unsigned short xl[18 * 16 * 68];  // 39168 B
    int t    = threadIdx.x;
    int bi   = blockIdx.x;
    int band = bi & 3;
    int g    = (bi >> 2) & 63;
    int b    = bi >> 8;
    int y0   = band * 16;

    // ---- stage x rows y0..y0+17 (clamped) -> LDS bf16 ----
    {
        int ci = t >> 4, part = t & 15;
        const float* xc = x + ((size_t)(b * 1024 + g * 16 + ci) * IPIX);
        #pragma unroll
        for (int s = 0; s < 18; ++s) {
            int row = y0 + s; if (row > 63) row = 63;
            float4v v = *(const float4v*)(xc + row * 64 + part * 4);
            unsigned short* dst = xl + (s * 16 + ci) * 68 + part * 4;
            dst[0] = f2bf(v[0]); dst[1] = f2bf(v[1]);
            dst[2] = f2bf(v[2]); dst[3] = f2bf(v[3]);
        }
    }
    // zero-pad px 64,65 (read by edge lanes of last x-tile)
    for (int e = t; e < 576; e += 256) {
        int r = e >> 5, rem = e & 31;
        xl[(r * 16 + (rem >> 1)) * 68 + 64 + (rem & 1)] = 0;
    }
    __syncthreads();

    // ---- compute: 4 waves x 16 tiles (16 px x 16 c0 each) ----
    int lane = t & 63, wv = t >> 6;
    int ln = lane & 15, quad = lane >> 4;

    short8 kf[5];
    #pragma unroll
    for (int f = 0; f < 5; ++f)
        kf[f] = *(const short8*)(kb + (f * 64 + lane) * 8);

    int ci0 = (quad & 1) * 8;
    for (int k = 0; k < 16; ++k) {
        int tid = wv * 16 + k;
        int yr = tid >> 2, xt = tid & 3, x0 = xt * 16;
        int yo = y0 + yr;
        float4v acc = {0.f, 0.f, 0.f, 0.f};
        #pragma unroll
        for (int f = 0; f < 5; ++f) {
            int tap = f * 2 + (quad >> 1);
            if (tap > 8) tap = 8;          // pad chunk: kb is zero there
            int dy = tap / 3, dx = tap % 3;
            const unsigned short* base = xl + ((yr + dy) * 16 + ci0) * 68 + x0 + dx + ln;
            short8 a;
            #pragma unroll
            for (int i = 0; i < 8; ++i) a[i] = (short)base[i * 68];
            acc = __builtin_amdgcn_mfma_f32_16x16x32_bf16(a, kf[f], acc, 0, 0, 0);
        }
        if (yo < OH) {
            // D: col = ln = c0, rows = px = x0 + quad*4 + r
            unsigned short* yp = y + ((size_t)(b * 1024 + g * 16 + ln) * 4096
                                      + yo * 64 + x0 + quad * 4);
            short4v o;
            o[0] = (short)f2bf(acc[0]); o[1] = (short)f2bf(acc[1]);
            o[2] = (short)f2bf(acc[2]); o[3] = (short)f2bf(acc[3]);
            *(short4v*)yp = o;
        }
    }
}

// ---------------------------------------------------------------------------
// mix3: SECOND stage. out[b][c0][pix][j] = bias[j] + sum_g y[b,(g,c0),pix]*Wm[g,j]
// The strided gather now runs on y: bf16, 64-px padded rows -> full 128-B
// cache-line segments per (g,c0) channel per block: HALF the line-touches of
// the old fp32 x-gather (the per-CU in-flight-line cap is the wall).
// LDS [px64][c0 16][chunk8^swz][gi8] bf16 = 128 KB; MFMA A = wmb [m=j][k=g],
// B = y-frags [k=g][n=c0] -> lane's 4 acc = consecutive j -> float4 stores.
// grid = 8b * 62 rows = 496 blocks of 512.
// ---------------------------------------------------------------------------
__global__ __launch_bounds__(512, 2) void mix3_kernel(const unsigned short* __restrict__ y,
                                                      const unsigned short* __restrict__ wmb,
                                                      const float* __restrict__ bias,
                                                      float* __restrict__ out) {
    __shared__ __align__(16) unsigned short yl[64 * 1024];  // 128 KB
    int t    = threadIdx.x;
    int bi   = blockIdx.x;
    int prow = bi % OH;
    int b    = bi / OH;

    // ---- stage y row-tile (64 px x 1024 ch) -> LDS, swizzled ----
    {
        int pq = t & 7, grp = t >> 3;                 // 8 px-octets x 64 groups
        const unsigned short* yb = y + ((size_t)b * 1024 * 4096) + prow * 64 + pq * 8;
        #pragma unroll
        for (int it = 0; it < 4; ++it) {
            int qd = it * 64 + grp;                   // 0..255: gq 0..15, c0 0..15
            int gq = qd & 15, c0 = qd >> 4;
            const unsigned short* yp = yb + (size_t)(gq * 4 * 16 + c0) * 4096;
            short8 v0 = *(const short8*)(yp);
            short8 v1 = *(const short8*)(yp + 16 * 4096);
            short8 v2 = *(const short8*)(yp + 32 * 4096);
            short8 v3 = *(const short8*)(yp + 48 * 4096);
            int chunk = gq >> 1;
            int gof   = (gq & 1) * 4;                 // g&7 base within chunk
            #pragma unroll
            for (int pp = 0; pp < 8; ++pp) {
                int px = pq * 8 + pp;
                int csw = chunk ^ (c0 & 7) ^ (pq & 7);
                short4v u;
                u[0] = v0[pp]; u[1] = v1[pp]; u[2] = v2[pp]; u[3] = v3[pp];
                *(short4v*)(yl + px * 1024 + c0 * 64 + csw * 8 + gof) = u;
            }
        }
    }
    __syncthreads();

    // ---- compute: 8 waves x 8 px ----
    int lane = t & 63, wv = t >> 6;
    int ln = lane & 15, quad = lane >> 4;

    short8 bf[8];
    #pragma unroll
    for (int q8 = 0; q8 < 8; ++q8)
        bf[q8] = *(const short8*)(wmb + (q8 * 64 + lane) * 8);  // [jt*2+kh]

    float4v bv[4];
    #pragma unroll
    for (int jt = 0; jt < 4; ++jt)
        bv[jt] = *(const float4v*)(bias + jt * 16 + quad * 4);

    for (int kk = 0; kk < 8; ++kk) {
        int pl = wv * 8 + kk;                         // px in tile = xout
        const unsigned short* arow = yl + pl * 1024 + ln * 64;
        int sx = (ln & 7) ^ ((pl >> 3) & 7);
        short8 a0 = *(const short8*)(arow + (((0 + quad) ^ sx) * 8));
        short8 a1 = *(const short8*)(arow + (((4 + quad) ^ sx) * 8));
        if (pl < OW) {
            float* ob = out + (((size_t)(b * 16 + ln) * OPIX) + prow * OW + pl) * NJ
                        + quad * 4;
            #pragma unroll
            for (int jt = 0; jt < 4; ++jt) {
                float4v acc = bv[jt];
                acc = __builtin_amdgcn_mfma_f32_16x16x32_bf16(bf[jt * 2 + 0], a0, acc, 0, 0, 0);
                acc = __builtin_amdgcn_mfma_f32_16x16x32_bf16(bf[jt * 2 + 1], a1, acc, 0, 0, 0);
                *(float4v*)(ob + jt * 16) = acc;
            }
        }
    }
}

// ---------------------------------------------------------------------------
// Fallback path (small ws): round-1 kernels, fp32 throughout.
// ---------------------------------------------------------------------------
__global__ __launch_bounds__(64) void wm_kernel(const float* __restrict__ core0,
                                                const float* __restrict__ core1,
                                                const float* __restrict__ core2,
                                                float* __restrict__ Wm) {
    int g = threadIdx.x;
    int i1 = g >> 4, i2 = (g >> 2) & 3, i3 = g & 3;
    for (int j = 0; j < NJ; ++j) {
        int j1 = j >> 4, j2 = (j >> 2) & 3, j3 = j & 3;
        float s = 0.f;
        #pragma unroll
        for (int r1 = 0; r1 < 8; ++r1) {
            float a = core0[(i1 * 4 + j1) * 8 + r1];
            float t = 0.f;
            #pragma unroll
            for (int r2 = 0; r2 < 8; ++r2) {
                t += core1[((r1 * 4 + i2) * 4 + j2) * 8 + r2] *
                     core2[(r2 * 4 + i3) * 4 + j3];
            }
            s += a * t;
        }
        Wm[g * NJ + j] = s;
    }
}

__global__ __launch_bounds__(256) void fused_fallback(const float* __restrict__ x,
                                                      const float* __restrict__ K,
                                                      const float* __restrict__ Wm,
                                                      const float* __restrict__ bias,
                                                      float* __restrict__ out) {
    __shared__ float wlds[NG * NJ];
    __shared__ float klds[NCI * 9];
    int blk  = blockIdx.x;
    int pblk = blk & 15;
    int c0   = (blk >> 4) & 15;
    int b    = blk >> 8;
    for (int i = threadIdx.x; i < NG * NJ; i += 256) wlds[i] = Wm[i];
    for (int i = threadIdx.x; i < NCI * 9; i += 256) klds[i] = K[c0 * NCI * 9 + i];
    __syncthreads();

    int pix = pblk * 256 + threadIdx.x;
    if (pix >= OPIX) return;
    int yy = pix / OW;
    int xx = pix % OW;

    float acc[NJ];
    #pragma unroll
    for (int j = 0; j < NJ; ++j) acc[j] = 0.f;

    for (int g = 0; g < NG; ++g) {
        float c = 0.f;
        const float* xb = x + ((size_t)(b * NG + g) * NCI) * IPIX;
        for (int ci = 0; ci < NCI; ++ci) {
            #pragma unroll
            for (int dy = 0; dy < 3; ++dy) {
                #pragma unroll
                for (int dx = 0; dx < 3; ++dx) {
                    c += xb[ci * IPIX + (yy + dy) * IW + (xx + dx)] *
                         klds[ci * 9 + dy * 3 + dx];
                }
            }
        }
        const float4* wp = (const float4*)&wlds[g * NJ];
        #pragma unroll
        for (int j4 = 0; j4 < 16; ++j4) {
            float4 w = wp[j4];
            acc[j4 * 4 + 0] += w.x * c;
            acc[j4 * 4 + 1] += w.y * c;
            acc[j4 * 4 + 2] += w.z * c;
            acc[j4 * 4 + 3] += w.w * c;
        }
    }
    #pragma unroll
    for (int j = 0; j < NJ; ++j) {
        out[(((size_t)(b * NC0 + c0) * OPIX) + pix) * NJ + j] = acc[j] + bias[j];
    }
}

extern "C" void kernel_launch(void* const* d_in, const int* in_sizes, int n_in,
                              void* d_out, int out_size, void* d_ws, size_t ws_size,
                              hipStream_t stream) {
    const float* x     = (const float*)d_in[0];
    const float* K     = (const float*)d_in[1];
    const float* core0 = (const float*)d_in[2];
    const float* core1 = (const float*)d_in[3];
    const float* core2 = (const float*)d_in[4];
    const float* bias  = (const float*)d_in[5];
    float* out = (float*)d_out;

    const size_t z_off   = 16384;
    const size_t z_bytes = (size_t)NB * 1024 * 4096 * sizeof(unsigned short);  // 67.1 MB

    if (ws_size >= z_off + z_bytes + 256) {
        unsigned short* wmb = (unsigned short*)d_ws;                    // 8 KB
        unsigned short* kb  = (unsigned short*)((char*)d_ws + 8192);    // 5 KB
        unsigned short* y   = (unsigned short*)((char*)d_ws + z_off);
        prep_kernel<<<9, 64, 0, stream>>>(K, core0, core1, core2, wmb, kb);
        conv1_kernel<<<NB * NG * 4, 256, 0, stream>>>(x, kb, y);
        mix3_kernel<<<NB * OH, 512, 0, stream>>>(y, wmb, bias, out);
    } else {
        float* Wm = (float*)d_ws;
        wm_kernel<<<1, 64, 0, stream>>>(core0, core1, core2, Wm);
        fused_fallback<<<NB * NC0 * 16, 256, 0, stream>>>(x, K, Wm, bias, out);
    }
}

// Round 7
// 99.100 us; speedup vs baseline: 1.4184x; 1.0045x over previous
//
#include <hip/hip_runtime.h>
#include <hip/hip_bf16.h>

// Problem constants
#define NB    8      // batch
#define NG    64     // c_inp groups (g)
#define NCI   16     // conv in channels (ci)
#define NC0   16     // conv out channels (c0)
#define NJ    64     // c_out (j)
#define IH    64
#define IW    64
#define OH    62
#define OW    62
#define IPIX  4096   // 64*64
#define OPIX  3844   // 62*62

typedef __attribute__((ext_vector_type(8))) short  short8;
typedef __attribute__((ext_vector_type(4))) short  short4v;
typedef __attribute__((ext_vector_type(4))) float  float4v;

__device__ __forceinline__ unsigned short f2bf(float f) {
    unsigned int u = __builtin_bit_cast(unsigned int, f);
    unsigned int r = (u + 0x7fffu + ((u >> 16) & 1u)) >> 16;
    return (unsigned short)r;
}

// ---------------------------------------------------------------------------
// prep: blocks 0..7 build Wm fragments (bf16) (jt = bi>>1, kh = bi&1)
//       block 8 builds conv K-fragments kb (K padded to 160 contraction, bf16)
// Fragment convention (16x16x32 bf16): free index = lane&15, k = (lane>>4)*8+i.
// ---------------------------------------------------------------------------
__global__ __launch_bounds__(64) void prep_kernel(const float* __restrict__ K,
                                                  const float* __restrict__ c0_,
                                                  const float* __restrict__ c1_,
                                                  const float* __restrict__ c2_,
                                                  unsigned short* __restrict__ wmb,
                                                  unsigned short* __restrict__ kb) {
    int bi = blockIdx.x;
    int l  = threadIdx.x;
    if (bi < 8) {
        int jt = bi >> 1, kh = bi & 1;
        int j = jt * 16 + (l & 15);
        int j1 = j >> 4, j2 = (j >> 2) & 3, j3 = j & 3;
        for (int i = 0; i < 8; ++i) {
            int g = kh * 32 + (l >> 4) * 8 + i;
            int i1 = g >> 4, i2 = (g >> 2) & 3, i3 = g & 3;
            float s = 0.f;
            #pragma unroll
            for (int r1 = 0; r1 < 8; ++r1) {
                float a = c0_[(i1 * 4 + j1) * 8 + r1];
                float t = 0.f;
                #pragma unroll
                for (int r2 = 0; r2 < 8; ++r2) {
                    t += c1_[((r1 * 4 + i2) * 4 + j2) * 8 + r2] *
                         c2_[(r2 * 4 + i3) * 4 + j3];
                }
                s += a * t;
            }
            wmb[(bi * 64 + l) * 8 + i] = f2bf(s);
        }
    } else {
        int c0i = l & 15, q = l >> 4;
        for (int f = 0; f < 5; ++f) {
            int tap = f * 2 + (q >> 1);  // 0..9; 9 = zero pad
            for (int i = 0; i < 8; ++i) {
                int ci = (q & 1) * 8 + i;
                float v = (tap < 9) ? K[(c0i * 16 + ci) * 9 + tap] : 0.f;
                kb[(f * 64 + l) * 8 + i] = f2bf(v);
            }
        }
    }
}

// ---------------------------------------------------------------------------
// conv1: FIRST stage (ops commuted: conv before mix, exact by linearity).
// y[b][g*16+c0][yo*64+xo] (bf16, 64-padded rows) =
//     sum_{ci,tap} K[c0,ci,tap] * x[b, g*16+ci, yo+dy, xo+dx]
//
// R7 change: LDS tile TRANSPOSED to [s 18][px 66 (stride 20us)][ci 16].
//  - A-fragment (8 contiguous ci) = two aligned ds_read_b64 instead of 8
//    scalar ds_read_u16  (640 -> 160 LDS reads per wave; R6 was LDS-bound).
//  - Staging: each thread loads float4 from FOUR ci rows (same aggregate
//    global pattern) and writes ONE b64 (4 ci) per px. px-stride = 40 B
//    (10 dwords, odd) => 64 write lanes hit 16 distinct 8-B slots across
//    512 B => conflict-free.
// Fragment k-order / MFMA order / f2bf points unchanged -> identical numerics.
// grid = 8*64*4 = 2048 blocks of 256.
// ---------------------------------------------------------------------------
#define PXS  20          // ushorts per px slot (40 B; slots 16..19 = pad)
#define ROWS 1320        // 66 * PXS ushorts per staged row

__global__ __launch_bounds__(256) void conv1_kernel(const float* __restrict__ x,
                                                    const unsigned short* __restrict__ kb,
                                                    unsigned short* __restrict__ y) {
    __shared__ unsigned short xl[18 * ROWS];  // 47520 B
    int t    = threadIdx.x;
    int bi   = blockIdx.x;
    int band = bi & 3;
    int g    = (bi >> 2) & 63;
    int b    = bi >> 8;
    int y0   = band * 16;

    // ---- stage x rows y0..y0+17 (clamped) -> LDS [s][px][ci] bf16 ----
    {
        int part = t & 15, cig = (t >> 4) & 3, sg = t >> 6;
        const float* xc = x + ((size_t)(b * 1024 + g * 16 + cig * 4) * IPIX) + part * 4;
        #pragma unroll
        for (int k = 0; k < 5; ++k) {
            int s = sg + k * 4;
            if (s < 18) {
                int row = y0 + s; if (row > 63) row = 63;
                const float* xr = xc + row * 64;
                float4v v0 = *(const float4v*)(xr);
                float4v v1 = *(const float4v*)(xr + IPIX);
                float4v v2 = *(const float4v*)(xr + 2 * IPIX);
                float4v v3 = *(const float4v*)(xr + 3 * IPIX);
                unsigned short* dst = xl + s * ROWS + (part * 4) * PXS + cig * 4;
                #pragma unroll
                for (int p = 0; p < 4; ++p) {
                    short4v u;
                    u[0] = (short)f2bf(v0[p]); u[1] = (short)f2bf(v1[p]);
                    u[2] = (short)f2bf(v2[p]); u[3] = (short)f2bf(v3[p]);
                    *(short4v*)(dst + p * PXS) = u;
                }
            }
        }
    }
    // zero-pad px 64,65 (read by edge tiles at dx>0)
    for (int e = t; e < 18 * 32; e += 256) {
        int s = e >> 5, rem = e & 31;     // rem = px(2) x ci(16)
        xl[s * ROWS + (64 + (rem >> 4)) * PXS + (rem & 15)] = 0;
    }
    __syncthreads();

    // ---- compute: 4 waves x 16 tiles (16 px x 16 c0 each) ----
    int lane = t & 63, wv = t >> 6;
    int ln = lane & 15, quad = lane >> 4;

    short8 kf[5];
    int off[5];
    #pragma unroll
    for (int f = 0; f < 5; ++f) {
        kf[f] = *(const short8*)(kb + (f * 64 + lane) * 8);
        int tap = f * 2 + (quad >> 1);
        if (tap > 8) tap = 8;             // pad chunk: kb is zero there
        int dy = tap / 3, dx = tap % 3;
        off[f] = dy * ROWS + dx * PXS;
    }
    int h8 = (quad & 1) * 8;

    for (int k = 0; k < 16; ++k) {
        int tid = wv * 16 + k;
        int yr = tid >> 2, x0 = (tid & 3) * 16;
        int yo = y0 + yr;
        const unsigned short* base = xl + yr * ROWS + (x0 + ln) * PXS + h8;
        float4v acc = {0.f, 0.f, 0.f, 0.f};
        #pragma unroll
        for (int f = 0; f < 5; ++f) {
            const unsigned short* p = base + off[f];
            short4v lo = *(const short4v*)(p);
            short4v hi = *(const short4v*)(p + 4);
            short8 a = __builtin_shufflevector(lo, hi, 0, 1, 2, 3, 4, 5, 6, 7);
            acc = __builtin_amdgcn_mfma_f32_16x16x32_bf16(a, kf[f], acc, 0, 0, 0);
        }
        if (yo < OH) {
            // D: col = ln = c0, rows = px = x0 + quad*4 + r
            unsigned short* yp = y + ((size_t)(b * 1024 + g * 16 + ln) * 4096
                                      + yo * 64 + x0 + quad * 4);
            short4v o;
            o[0] = (short)f2bf(acc[0]); o[1] = (short)f2bf(acc[1]);
            o[2] = (short)f2bf(acc[2]); o[3] = (short)f2bf(acc[3]);
            *(short4v*)yp = o;
        }
    }
}

// ---------------------------------------------------------------------------
// mix3: SECOND stage. out[b][c0][pix][j] = bias[j] + sum_g y[b,(g,c0),pix]*Wm[g,j]
// Full-128-B-line bf16 gather on L3-resident y; at its write-roofline (~20us).
// grid = 8b * 62 rows = 496 blocks of 512.
// ---------------------------------------------------------------------------
__global__ __launch_bounds__(512, 2) void mix3_kernel(const unsigned short* __restrict__ y,
                                                      const unsigned short* __restrict__ wmb,
                                                      const float* __restrict__ bias,
                                                      float* __restrict__ out) {
    __shared__ __align__(16) unsigned short yl[64 * 1024];  // 128 KB
    int t    = threadIdx.x;
    int bi   = blockIdx.x;
    int prow = bi % OH;
    int b    = bi / OH;

    // ---- stage y row-tile (64 px x 1024 ch) -> LDS, swizzled ----
    {
        int pq = t & 7, grp = t >> 3;                 // 8 px-octets x 64 groups
        const unsigned short* yb = y + ((size_t)b * 1024 * 4096) + prow * 64 + pq * 8;
        #pragma unroll
        for (int it = 0; it < 4; ++it) {
            int qd = it * 64 + grp;                   // 0..255: gq 0..15, c0 0..15
            int gq = qd & 15, c0 = qd >> 4;
            const unsigned short* yp = yb + (size_t)(gq * 4 * 16 + c0) * 4096;
            short8 v0 = *(const short8*)(yp);
            short8 v1 = *(const short8*)(yp + 16 * 4096);
            short8 v2 = *(const short8*)(yp + 32 * 4096);
            short8 v3 = *(const short8*)(yp + 48 * 4096);
            int chunk = gq >> 1;
            int gof   = (gq & 1) * 4;                 // g&7 base within chunk
            #pragma unroll
            for (int pp = 0; pp < 8; ++pp) {
                int px = pq * 8 + pp;
                int csw = chunk ^ (c0 & 7) ^ (pq & 7);
                short4v u;
                u[0] = v0[pp]; u[1] = v1[pp]; u[2] = v2[pp]; u[3] = v3[pp];
                *(short4v*)(yl + px * 1024 + c0 * 64 + csw * 8 + gof) = u;
            }
        }
    }
    __syncthreads();

    // ---- compute: 8 waves x 8 px ----
    int lane = t & 63, wv = t >> 6;
    int ln = lane & 15, quad = lane >> 4;

    short8 bf[8];
    #pragma unroll
    for (int q8 = 0; q8 < 8; ++q8)
        bf[q8] = *(const short8*)(wmb + (q8 * 64 + lane) * 8);  // [jt*2+kh]

    float4v bv[4];
    #pragma unroll
    for (int jt = 0; jt < 4; ++jt)
        bv[jt] = *(const float4v*)(bias + jt * 16 + quad * 4);

    for (int kk = 0; kk < 8; ++kk) {
        int pl = wv * 8 + kk;                         // px in tile = xout
        const unsigned short* arow = yl + pl * 1024 + ln * 64;
        int sx = (ln & 7) ^ ((pl >> 3) & 7);
        short8 a0 = *(const short8*)(arow + (((0 + quad) ^ sx) * 8));
        short8 a1 = *(const short8*)(arow + (((4 + quad) ^ sx) * 8));
        if (pl < OW) {
            float* ob = out + (((size_t)(b * 16 + ln) * OPIX) + prow * OW + pl) * NJ
                        + quad * 4;
            #pragma unroll
            for (int jt = 0; jt < 4; ++jt) {
                float4v acc = bv[jt];
                acc = __builtin_amdgcn_mfma_f32_16x16x32_bf16(bf[jt * 2 + 0], a0, acc, 0, 0, 0);
                acc = __builtin_amdgcn_mfma_f32_16x16x32_bf16(bf[jt * 2 + 1], a1, acc, 0, 0, 0);
                *(float4v*)(ob + jt * 16) = acc;
            }
        }
    }
}

// ---------------------------------------------------------------------------
// Fallback path (small ws): round-1 kernels, fp32 throughout.
// ---------------------------------------------------------------------------
__global__ __launch_bounds__(64) void wm_kernel(const float* __restrict__ core0,
                                                const float* __restrict__ core1,
                                                const float* __restrict__ core2,
                                                float* __restrict__ Wm) {
    int g = threadIdx.x;
    int i1 = g >> 4, i2 = (g >> 2) & 3, i3 = g & 3;
    for (int j = 0; j < NJ; ++j) {
        int j1 = j >> 4, j2 = (j >> 2) & 3, j3 = j & 3;
        float s = 0.f;
        #pragma unroll
        for (int r1 = 0; r1 < 8; ++r1) {
            float a = core0[(i1 * 4 + j1) * 8 + r1];
            float t = 0.f;
            #pragma unroll
            for (int r2 = 0; r2 < 8; ++r2) {
                t += core1[((r1 * 4 + i2) * 4 + j2) * 8 + r2] *
                     core2[(r2 * 4 + i3) * 4 + j3];
            }
            s += a * t;
        }
        Wm[g * NJ + j] = s;
    }
}

__global__ __launch_bounds__(256) void fused_fallback(const float* __restrict__ x,
                                                      const float* __restrict__ K,
                                                      const float* __restrict__ Wm,
                                                      const float* __restrict__ bias,
                                                      float* __restrict__ out) {
    __shared__ float wlds[NG * NJ];
    __shared__ float klds[NCI * 9];
    int blk  = blockIdx.x;
    int pblk = blk & 15;
    int c0   = (blk >> 4) & 15;
    int b    = blk >> 8;
    for (int i = threadIdx.x; i < NG * NJ; i += 256) wlds[i] = Wm[i];
    for (int i = threadIdx.x; i < NCI * 9; i += 256) klds[i] = K[c0 * NCI * 9 + i];
    __syncthreads();

    int pix = pblk * 256 + threadIdx.x;
    if (pix >= OPIX) return;
    int yy = pix / OW;
    int xx = pix % OW;

    float acc[NJ];
    #pragma unroll
    for (int j = 0; j < NJ; ++j) acc[j] = 0.f;

    for (int g = 0; g < NG; ++g) {
        float c = 0.f;
        const float* xb = x + ((size_t)(b * NG + g) * NCI) * IPIX;
        for (int ci = 0; ci < NCI; ++ci) {
            #pragma unroll
            for (int dy = 0; dy < 3; ++dy) {
                #pragma unroll
                for (int dx = 0; dx < 3; ++dx) {
                    c += xb[ci * IPIX + (yy + dy) * IW + (xx + dx)] *
                         klds[ci * 9 + dy * 3 + dx];
                }
            }
        }
        const float4* wp = (const float4*)&wlds[g * NJ];
        #pragma unroll
        for (int j4 = 0; j4 < 16; ++j4) {
            float4 w = wp[j4];
            acc[j4 * 4 + 0] += w.x * c;
            acc[j4 * 4 + 1] += w.y * c;
            acc[j4 * 4 + 2] += w.z * c;
            acc[j4 * 4 + 3] += w.w * c;
        }
    }
    #pragma unroll
    for (int j = 0; j < NJ; ++j) {
        out[(((size_t)(b * NC0 + c0) * OPIX) + pix) * NJ + j] = acc[j] + bias[j];
    }
}

extern "C" void kernel_launch(void* const* d_in, const int* in_sizes, int n_in,
                              void* d_out, int out_size, void* d_ws, size_t ws_size,
                              hipStream_t stream) {
    const float* x     = (const float*)d_in[0];
    const float* K     = (const float*)d_in[1];
    const float* core0 = (const float*)d_in[2];
    const float* core1 = (const float*)d_in[3];
    const float* core2 = (const float*)d_in[4];
    const float* bias  = (const float*)d_in[5];
    float* out = (float*)d_out;

    const size_t z_off   = 16384;
    const size_t z_bytes = (size_t)NB * 1024 * 4096 * sizeof(unsigned short);  // 67.1 MB

    if (ws_size >= z_off + z_bytes + 256) {
        unsigned short* wmb = (unsigned short*)d_ws;                    // 8 KB
        unsigned short* kb  = (unsigned short*)((char*)d_ws + 8192);    // 5 KB
        unsigned short* y   = (unsigned short*)((char*)d_ws + z_off);
        prep_kernel<<<9, 64, 0, stream>>>(K, core0, core1, core2, wmb, kb);
        conv1_kernel<<<NB * NG * 4, 256, 0, stream>>>(x, kb, y);
        mix3_kernel<<<NB * OH, 512, 0, stream>>>(y, wmb, bias, out);
    } else {
        float* Wm = (float*)d_ws;
        wm_kernel<<<1, 64, 0, stream>>>(core0, core1, core2, Wm);
        fused_fallback<<<NB * NC0 * 16, 256, 0, stream>>>(x, K, Wm, bias, out);
    }
}

// Round 8
// 94.175 us; speedup vs baseline: 1.4925x; 1.0523x over previous
//
#include <hip/hip_runtime.h>
#include <hip/hip_bf16.h>

// Problem constants
#define NB    8      // batch
#define NG    64     // c_inp groups (g)
#define NCI   16     // conv in channels (ci)
#define NC0   16     // conv out channels (c0)
#define NJ    64     // c_out (j)
#define IH    64
#define IW    64
#define OH    62
#define OW    62
#define IPIX  4096   // 64*64
#define OPIX  3844   // 62*62

typedef __attribute__((ext_vector_type(8))) short  short8;
typedef __attribute__((ext_vector_type(4))) short  short4v;
typedef __attribute__((ext_vector_type(4))) float  float4v;

__device__ __forceinline__ unsigned short f2bf(float f) {
    unsigned int u = __builtin_bit_cast(unsigned int, f);
    unsigned int r = (u + 0x7fffu + ((u >> 16) & 1u)) >> 16;
    return (unsigned short)r;
}

// ---------------------------------------------------------------------------
// prep: blocks 0..7 build Wm fragments (bf16) (jt = bi>>1, kh = bi&1)
//       block 8 builds conv K-fragments kb (K padded to 160 contraction, bf16)
// Fragment convention (16x16x32 bf16): free index = lane&15, k = (lane>>4)*8+i.
// ---------------------------------------------------------------------------
__global__ __launch_bounds__(64) void prep_kernel(const float* __restrict__ K,
                                                  const float* __restrict__ c0_,
                                                  const float* __restrict__ c1_,
                                                  const float* __restrict__ c2_,
                                                  unsigned short* __restrict__ wmb,
                                                  unsigned short* __restrict__ kb) {
    int bi = blockIdx.x;
    int l  = threadIdx.x;
    if (bi < 8) {
        int jt = bi >> 1, kh = bi & 1;
        int j = jt * 16 + (l & 15);
        int j1 = j >> 4, j2 = (j >> 2) & 3, j3 = j & 3;
        for (int i = 0; i < 8; ++i) {
            int g = kh * 32 + (l >> 4) * 8 + i;
            int i1 = g >> 4, i2 = (g >> 2) & 3, i3 = g & 3;
            float s = 0.f;
            #pragma unroll
            for (int r1 = 0; r1 < 8; ++r1) {
                float a = c0_[(i1 * 4 + j1) * 8 + r1];
                float t = 0.f;
                #pragma unroll
                for (int r2 = 0; r2 < 8; ++r2) {
                    t += c1_[((r1 * 4 + i2) * 4 + j2) * 8 + r2] *
                         c2_[(r2 * 4 + i3) * 4 + j3];
                }
                s += a * t;
            }
            wmb[(bi * 64 + l) * 8 + i] = f2bf(s);
        }
    } else {
        int c0i = l & 15, q = l >> 4;
        for (int f = 0; f < 5; ++f) {
            int tap = f * 2 + (q >> 1);  // 0..9; 9 = zero pad
            for (int i = 0; i < 8; ++i) {
                int ci = (q & 1) * 8 + i;
                float v = (tap < 9) ? K[(c0i * 16 + ci) * 9 + tap] : 0.f;
                kb[(f * 64 + l) * 8 + i] = f2bf(v);
            }
        }
    }
}

// ---------------------------------------------------------------------------
// conv1: FIRST stage (ops commuted: conv before mix, exact by linearity).
// y[b][g*16+c0][yo*64+xo] (bf16, 64-padded rows) =
//     sum_{ci,tap} K[c0,ci,tap] * x[b, g*16+ci, yo+dy, xo+dx]
//
// R8 change: band 16 -> 8 output rows per block. LDS 47.6 -> 26.4 KB ->
// 6 blocks/CU (was 3), 24 waves/CU. R7 evidence: conv1 is latency-chain
// bound (dur insensitive to HBM traffic, everything idle, and R6->R7
// regression tracked the 4->3 blocks/CU drop). Staging chains shorten
// (2.5 vs 5 dependent iterations) and 2x blocks overlap them.
// LDS tile [s 10][px 66 (stride 20us)][ci 16]; fragment = 2x ds_read_b64.
// Fragment k-order / MFMA order / f2bf points unchanged -> identical numerics.
// grid = 8*64*8 = 4096 blocks of 256.
// ---------------------------------------------------------------------------
#define PXS  20          // ushorts per px slot (40 B; slots 16..19 = pad)
#define ROWS 1320        // 66 * PXS ushorts per staged row

__global__ __launch_bounds__(256, 6) void conv1_kernel(const float* __restrict__ x,
                                                       const unsigned short* __restrict__ kb,
                                                       unsigned short* __restrict__ y) {
    __shared__ unsigned short xl[10 * ROWS];  // 26400 B
    int t    = threadIdx.x;
    int bi   = blockIdx.x;
    int band = bi & 7;
    int g    = (bi >> 3) & 63;
    int b    = bi >> 9;
    int y0   = band * 8;

    // ---- stage x rows y0..y0+9 (clamped) -> LDS [s][px][ci] bf16 ----
    {
        int part = t & 15, cig = (t >> 4) & 3, sg = t >> 6;
        const float* xc = x + ((size_t)(b * 1024 + g * 16 + cig * 4) * IPIX) + part * 4;
        #pragma unroll
        for (int k = 0; k < 3; ++k) {
            int s = sg + k * 4;
            if (s < 10) {
                int row = y0 + s; if (row > 63) row = 63;  // only feeds discarded yo>=62
                const float* xr = xc + row * 64;
                float4v v0 = *(const float4v*)(xr);
                float4v v1 = *(const float4v*)(xr + IPIX);
                float4v v2 = *(const float4v*)(xr + 2 * IPIX);
                float4v v3 = *(const float4v*)(xr + 3 * IPIX);
                unsigned short* dst = xl + s * ROWS + (part * 4) * PXS + cig * 4;
                #pragma unroll
                for (int p = 0; p < 4; ++p) {
                    short4v u;
                    u[0] = (short)f2bf(v0[p]); u[1] = (short)f2bf(v1[p]);
                    u[2] = (short)f2bf(v2[p]); u[3] = (short)f2bf(v3[p]);
                    *(short4v*)(dst + p * PXS) = u;
                }
            }
        }
    }
    // zero-pad px 64,65 (read by edge tiles at dx>0)
    for (int e = t; e < 10 * 32; e += 256) {
        int s = e >> 5, rem = e & 31;     // rem = px(2) x ci(16)
        xl[s * ROWS + (64 + (rem >> 4)) * PXS + (rem & 15)] = 0;
    }
    __syncthreads();

    // ---- compute: 4 waves x 8 tiles (16 px x 16 c0 each) ----
    int lane = t & 63, wv = t >> 6;
    int ln = lane & 15, quad = lane >> 4;

    short8 kf[5];
    int off[5];
    #pragma unroll
    for (int f = 0; f < 5; ++f) {
        kf[f] = *(const short8*)(kb + (f * 64 + lane) * 8);
        int tap = f * 2 + (quad >> 1);
        if (tap > 8) tap = 8;             // pad chunk: kb is zero there
        int dy = tap / 3, dx = tap % 3;
        off[f] = dy * ROWS + dx * PXS;
    }
    int h8 = (quad & 1) * 8;

    for (int k = 0; k < 8; ++k) {
        int tid = wv * 8 + k;
        int yr = tid >> 2, x0 = (tid & 3) * 16;
        int yo = y0 + yr;
        const unsigned short* base = xl + yr * ROWS + (x0 + ln) * PXS + h8;
        float4v acc = {0.f, 0.f, 0.f, 0.f};
        #pragma unroll
        for (int f = 0; f < 5; ++f) {
            const unsigned short* p = base + off[f];
            short4v lo = *(const short4v*)(p);
            short4v hi = *(const short4v*)(p + 4);
            short8 a = __builtin_shufflevector(lo, hi, 0, 1, 2, 3, 4, 5, 6, 7);
            acc = __builtin_amdgcn_mfma_f32_16x16x32_bf16(a, kf[f], acc, 0, 0, 0);
        }
        if (yo < OH) {
            // D: col = ln = c0, rows = px = x0 + quad*4 + r
            unsigned short* yp = y + ((size_t)(b * 1024 + g * 16 + ln) * 4096
                                      + yo * 64 + x0 + quad * 4);
            short4v o;
            o[0] = (short)f2bf(acc[0]); o[1] = (short)f2bf(acc[1]);
            o[2] = (short)f2bf(acc[2]); o[3] = (short)f2bf(acc[3]);
            *(short4v*)yp = o;
        }
    }
}

// ---------------------------------------------------------------------------
// mix3: SECOND stage. out[b][c0][pix][j] = bias[j] + sum_g y[b,(g,c0),pix]*Wm[g,j]
// Full-128-B-line bf16 gather on L3-resident y; at its write-roofline (~20us).
// grid = 8b * 62 rows = 496 blocks of 512.
// ---------------------------------------------------------------------------
__global__ __launch_bounds__(512, 2) void mix3_kernel(const unsigned short* __restrict__ y,
                                                      const unsigned short* __restrict__ wmb,
                                                      const float* __restrict__ bias,
                                                      float* __restrict__ out) {
    __shared__ __align__(16) unsigned short yl[64 * 1024];  // 128 KB
    int t    = threadIdx.x;
    int bi   = blockIdx.x;
    int prow = bi % OH;
    int b    = bi / OH;

    // ---- stage y row-tile (64 px x 1024 ch) -> LDS, swizzled ----
    {
        int pq = t & 7, grp = t >> 3;                 // 8 px-octets x 64 groups
        const unsigned short* yb = y + ((size_t)b * 1024 * 4096) + prow * 64 + pq * 8;
        #pragma unroll
        for (int it = 0; it < 4; ++it) {
            int qd = it * 64 + grp;                   // 0..255: gq 0..15, c0 0..15
            int gq = qd & 15, c0 = qd >> 4;
            const unsigned short* yp = yb + (size_t)(gq * 4 * 16 + c0) * 4096;
            short8 v0 = *(const short8*)(yp);
            short8 v1 = *(const short8*)(yp + 16 * 4096);
            short8 v2 = *(const short8*)(yp + 32 * 4096);
            short8 v3 = *(const short8*)(yp + 48 * 4096);
            int chunk = gq >> 1;
            int gof   = (gq & 1) * 4;                 // g&7 base within chunk
            #pragma unroll
            for (int pp = 0; pp < 8; ++pp) {
                int px = pq * 8 + pp;
                int csw = chunk ^ (c0 & 7) ^ (pq & 7);
                short4v u;
                u[0] = v0[pp]; u[1] = v1[pp]; u[2] = v2[pp]; u[3] = v3[pp];
                *(short4v*)(yl + px * 1024 + c0 * 64 + csw * 8 + gof) = u;
            }
        }
    }
    __syncthreads();

    // ---- compute: 8 waves x 8 px ----
    int lane = t & 63, wv = t >> 6;
    int ln = lane & 15, quad = lane >> 4;

    short8 bf[8];
    #pragma unroll
    for (int q8 = 0; q8 < 8; ++q8)
        bf[q8] = *(const short8*)(wmb + (q8 * 64 + lane) * 8);  // [jt*2+kh]

    float4v bv[4];
    #pragma unroll
    for (int jt = 0; jt < 4; ++jt)
        bv[jt] = *(const float4v*)(bias + jt * 16 + quad * 4);

    for (int kk = 0; kk < 8; ++kk) {
        int pl = wv * 8 + kk;                         // px in tile = xout
        const unsigned short* arow = yl + pl * 1024 + ln * 64;
        int sx = (ln & 7) ^ ((pl >> 3) & 7);
        short8 a0 = *(const short8*)(arow + (((0 + quad) ^ sx) * 8));
        short8 a1 = *(const short8*)(arow + (((4 + quad) ^ sx) * 8));
        if (pl < OW) {
            float* ob = out + (((size_t)(b * 16 + ln) * OPIX) + prow * OW + pl) * NJ
                        + quad * 4;
            #pragma unroll
            for (int jt = 0; jt < 4; ++jt) {
                float4v acc = bv[jt];
                acc = __builtin_amdgcn_mfma_f32_16x16x32_bf16(bf[jt * 2 + 0], a0, acc, 0, 0, 0);
                acc = __builtin_amdgcn_mfma_f32_16x16x32_bf16(bf[jt * 2 + 1], a1, acc, 0, 0, 0);
                *(float4v*)(ob + jt * 16) = acc;
            }
        }
    }
}

// ---------------------------------------------------------------------------
// Fallback path (small ws): round-1 kernels, fp32 throughout.
// ---------------------------------------------------------------------------
__global__ __launch_bounds__(64) void wm_kernel(const float* __restrict__ core0,
                                                const float* __restrict__ core1,
                                                const float* __restrict__ core2,
                                                float* __restrict__ Wm) {
    int g = threadIdx.x;
    int i1 = g >> 4, i2 = (g >> 2) & 3, i3 = g & 3;
    for (int j = 0; j < NJ; ++j) {
        int j1 = j >> 4, j2 = (j >> 2) & 3, j3 = j & 3;
        float s = 0.f;
        #pragma unroll
        for (int r1 = 0; r1 < 8; ++r1) {
            float a = core0[(i1 * 4 + j1) * 8 + r1];
            float t = 0.f;
            #pragma unroll
            for (int r2 = 0; r2 < 8; ++r2) {
                t += core1[((r1 * 4 + i2) * 4 + j2) * 8 + r2] *
                     core2[(r2 * 4 + i3) * 4 + j3];
            }
            s += a * t;
        }
        Wm[g * NJ + j] = s;
    }
}

__global__ __launch_bounds__(256) void fused_fallback(const float* __restrict__ x,
                                                      const float* __restrict__ K,
                                                      const float* __restrict__ Wm,
                                                      const float* __restrict__ bias,
                                                      float* __restrict__ out) {
    __shared__ float wlds[NG * NJ];
    __shared__ float klds[NCI * 9];
    int blk  = blockIdx.x;
    int pblk = blk & 15;
    int c0   = (blk >> 4) & 15;
    int b    = blk >> 8;
    for (int i = threadIdx.x; i < NG * NJ; i += 256) wlds[i] = Wm[i];
    for (int i = threadIdx.x; i < NCI * 9; i += 256) klds[i] = K[c0 * NCI * 9 + i];
    __syncthreads();

    int pix = pblk * 256 + threadIdx.x;
    if (pix >= OPIX) return;
    int yy = pix / OW;
    int xx = pix % OW;

    float acc[NJ];
    #pragma unroll
    for (int j = 0; j < NJ; ++j) acc[j] = 0.f;

    for (int g = 0; g < NG; ++g) {
        float c = 0.f;
        const float* xb = x + ((size_t)(b * NG + g) * NCI) * IPIX;
        for (int ci = 0; ci < NCI; ++ci) {
            #pragma unroll
            for (int dy = 0; dy < 3; ++dy) {
                #pragma unroll
                for (int dx = 0; dx < 3; ++dx) {
                    c += xb[ci * IPIX + (yy + dy) * IW + (xx + dx)] *
                         klds[ci * 9 + dy * 3 + dx];
                }
            }
        }
        const float4* wp = (const float4*)&wlds[g * NJ];
        #pragma unroll
        for (int j4 = 0; j4 < 16; ++j4) {
            float4 w = wp[j4];
            acc[j4 * 4 + 0] += w.x * c;
            acc[j4 * 4 + 1] += w.y * c;
            acc[j4 * 4 + 2] += w.z * c;
            acc[j4 * 4 + 3] += w.w * c;
        }
    }
    #pragma unroll
    for (int j = 0; j < NJ; ++j) {
        out[(((size_t)(b * NC0 + c0) * OPIX) + pix) * NJ + j] = acc[j] + bias[j];
    }
}

extern "C" void kernel_launch(void* const* d_in, const int* in_sizes, int n_in,
                              void* d_out, int out_size, void* d_ws, size_t ws_size,
                              hipStream_t stream) {
    const float* x     = (const float*)d_in[0];
    const float* K     = (const float*)d_in[1];
    const float* core0 = (const float*)d_in[2];
    const float* core1 = (const float*)d_in[3];
    const float* core2 = (const float*)d_in[4];
    const float* bias  = (const float*)d_in[5];
    float* out = (float*)d_out;

    const size_t z_off   = 16384;
    const size_t z_bytes = (size_t)NB * 1024 * 4096 * sizeof(unsigned short);  // 67.1 MB

    if (ws_size >= z_off + z_bytes + 256) {
        unsigned short* wmb = (unsigned short*)d_ws;                    // 8 KB
        unsigned short* kb  = (unsigned short*)((char*)d_ws + 8192);    // 5 KB
        unsigned short* y   = (unsigned short*)((char*)d_ws + z_off);
        prep_kernel<<<9, 64, 0, stream>>>(K, core0, core1, core2, wmb, kb);
        conv1_kernel<<<NB * NG * 8, 256, 0, stream>>>(x, kb, y);
        mix3_kernel<<<NB * OH, 512, 0, stream>>>(y, wmb, bias, out);
    } else {
        float* Wm = (float*)d_ws;
        wm_kernel<<<1, 64, 0, stream>>>(core0, core1, core2, Wm);
        fused_fallback<<<NB * NC0 * 16, 256, 0, stream>>>(x, K, Wm, bias, out);
    }
}